// Round 2
// baseline (191.328 us; speedup 1.0000x reference)
//
#include <hip/hip_runtime.h>
#include <math.h>

#define NLIG 512
#define NPROT 2048
#define NTOT 2560
#define LFE 16
#define PFE 21
#define JFE 16
#define HME 16
#define DD 17   // JF+1

// ws layout in floats
#define B_OFF   0          // NTOT*16 = 40960
#define PB_OFF  40960      // NTOT*4  = 10240 (float4: x,y,z,batch-as-int)
#define A_OFF   51200      // NLIG*16 = 8192  (a_i + be)
#define H_OFF   59392      // NLIG*17 = 8704
// total 68096 floats = 272,384 bytes of ws

__device__ __forceinline__ float silu_f(float x) {
    return x / (1.0f + __expf(-x));
}

__global__ __launch_bounds__(256) void encode_kernel(
    const float* __restrict__ xl, const float* __restrict__ xp,
    const float* __restrict__ posl, const float* __restrict__ posp,
    const float* __restrict__ t,
    const int* __restrict__ bl, const int* __restrict__ bp,
    const int* __restrict__ lmask,
    const float* __restrict__ aW1, const float* __restrict__ ab1,
    const float* __restrict__ aW2, const float* __restrict__ ab2,
    const float* __restrict__ fW1, const float* __restrict__ fb1,
    const float* __restrict__ fW2, const float* __restrict__ fb2,
    const float* __restrict__ rW1, const float* __restrict__ rb1,
    const float* __restrict__ rW2, const float* __restrict__ rb2,
    const float* __restrict__ We, const float* __restrict__ be,
    float* __restrict__ ws)
{
    int i = blockIdx.x * 256 + threadIdx.x;
    if (i >= NTOT) return;

    float h[DD];
    if (i < NLIG) {
        float x[LFE];
        #pragma unroll
        for (int k = 0; k < LFE; ++k) x[k] = xl[i * LFE + k];
        bool am = (lmask[i] != 0);
        const float* W1 = am ? aW1 : fW1;
        const float* b1 = am ? ab1 : fb1;
        const float* W2 = am ? aW2 : fW2;
        const float* b2 = am ? ab2 : fb2;
        float hid[2 * LFE];
        #pragma unroll
        for (int c = 0; c < 2 * LFE; ++c) {
            float s = b1[c];
            #pragma unroll
            for (int k = 0; k < LFE; ++k) s += x[k] * W1[k * (2 * LFE) + c];
            hid[c] = silu_f(s);
        }
        #pragma unroll
        for (int o = 0; o < JFE; ++o) {
            float s = b2[o];
            #pragma unroll
            for (int c = 0; c < 2 * LFE; ++c) s += hid[c] * W2[c * JFE + o];
            h[o] = s;
        }
    } else {
        int ip = i - NLIG;
        float x[PFE];
        #pragma unroll
        for (int k = 0; k < PFE; ++k) x[k] = xp[ip * PFE + k];
        float hid[2 * PFE];
        #pragma unroll
        for (int c = 0; c < 2 * PFE; ++c) {
            float s = rb1[c];
            #pragma unroll
            for (int k = 0; k < PFE; ++k) s += x[k] * rW1[k * (2 * PFE) + c];
            hid[c] = silu_f(s);
        }
        #pragma unroll
        for (int o = 0; o < JFE; ++o) {
            float s = rb2[o];
            #pragma unroll
            for (int c = 0; c < 2 * PFE; ++c) s += hid[c] * rW2[c * JFE + o];
            h[o] = s;
        }
    }
    h[DD - 1] = t[0];

    // b_j = h . We[D:2D]  (all nodes)
    #pragma unroll
    for (int m = 0; m < HME; ++m) {
        float s = 0.0f;
        #pragma unroll
        for (int k = 0; k < DD; ++k) s += h[k] * We[(DD + k) * HME + m];
        ws[B_OFF + i * HME + m] = s;
    }

    // packed pos + batch
    float px, py, pz; int bt;
    if (i < NLIG) { px = posl[i*3]; py = posl[i*3+1]; pz = posl[i*3+2]; bt = bl[i]; }
    else { int ip = i - NLIG; px = posp[ip*3]; py = posp[ip*3+1]; pz = posp[ip*3+2]; bt = bp[ip]; }
    ((float4*)(ws + PB_OFF))[i] = make_float4(px, py, pz, __int_as_float(bt));

    if (i < NLIG) {
        // a_i = h . We[:D] + be   (ligand rows are the only i we need)
        #pragma unroll
        for (int m = 0; m < HME; ++m) {
            float s = be[m];
            #pragma unroll
            for (int k = 0; k < DD; ++k) s += h[k] * We[k * HME + m];
            ws[A_OFF + i * HME + m] = s;
        }
        #pragma unroll
        for (int k = 0; k < DD; ++k) ws[H_OFF + i * DD + k] = h[k];
    }
}

// one wave (64 lanes) per ligand node i.
// Batch b's same-batch j-domain is [64b,64b+64) (ligand) U [512+256b,+256) (protein):
// exactly 5 wave-iterations, no batch test needed.
// After butterfly-reduce, the wave redundantly computes node i's decode and lane 0 writes.
__global__ __launch_bounds__(256) void pair_decode_kernel(
    const float* __restrict__ We, const float* __restrict__ Wx,
    const float* __restrict__ bx,
    const int* __restrict__ lmask,
    const float* __restrict__ Wh, const float* __restrict__ bh,
    const float* __restrict__ dW1, const float* __restrict__ db1,
    const float* __restrict__ dW2, const float* __restrict__ db2,
    float* __restrict__ ws, float* __restrict__ out)
{
    int i = blockIdx.x * 4 + (threadIdx.x >> 6);
    int lane = threadIdx.x & 63;
    if (i >= NLIG) return;

    const float* Bv = ws + B_OFF;
    const float4* PB = (const float4*)(ws + PB_OFF);
    float4 pi = PB[i];
    int b = i >> 6;   // ligand batch id (64 ligand nodes per batch)

    float Ai[HME], w2[HME], wx[HME];
    #pragma unroll
    for (int m = 0; m < HME; ++m) {
        Ai[m] = ws[A_OFF + i * HME + m];
        w2[m] = We[2 * DD * HME + m];   // row 2D of We (d2 coefficient)
        wx[m] = Wx[m];
    }
    float bxv = bx[0];

    float agg[HME];
    #pragma unroll
    for (int m = 0; m < HME; ++m) agg[m] = 0.0f;
    float tx = 0.0f, ty = 0.0f, tz = 0.0f;

    int js[5];
    js[0] = b * 64 + lane;                    // own-batch ligand block
    #pragma unroll
    for (int k = 0; k < 4; ++k) js[k + 1] = NLIG + b * 256 + k * 64 + lane;

    #pragma unroll
    for (int it = 0; it < 5; ++it) {
        int j = js[it];
        float4 pj = PB[j];
        float dx = pi.x - pj.x, dy = pi.y - pj.y, dz = pi.z - pj.z;
        float d2 = dx * dx + dy * dy + dz * dz;
        if (d2 < 25.0f) {
            const float4* bj4 = (const float4*)(Bv + j * HME);
            float bj[HME];
            *(float4*)(bj + 0)  = bj4[0];
            *(float4*)(bj + 4)  = bj4[1];
            *(float4*)(bj + 8)  = bj4[2];
            *(float4*)(bj + 12) = bj4[3];
            float e = bxv;
            #pragma unroll
            for (int m = 0; m < HME; ++m) {
                float pre = Ai[m] + bj[m] + d2 * w2[m];
                float s = silu_f(pre);
                agg[m] += s;
                e += s * wx[m];
            }
            tx += dx * e; ty += dy * e; tz += dz * e;
        }
    }

    // butterfly reduce -> ALL lanes hold the full sums
    #pragma unroll
    for (int off = 1; off <= 32; off <<= 1) {
        #pragma unroll
        for (int m = 0; m < HME; ++m) agg[m] += __shfl_xor(agg[m], off, 64);
        tx += __shfl_xor(tx, off, 64);
        ty += __shfl_xor(ty, off, 64);
        tz += __shfl_xor(tz, off, 64);
    }

    // --- decode for node i (redundant across lanes; uniform -> no divergence) ---
    bool msk = (lmask[i] != 0);

    float hfull[DD];
    #pragma unroll
    for (int k = 0; k < DD; ++k) hfull[k] = ws[H_OFF + i * DD + k];

    float ho[JFE];
    #pragma unroll
    for (int c = 0; c < JFE; ++c) {
        float s = bh[c];
        #pragma unroll
        for (int k = 0; k < DD; ++k) s += hfull[k] * Wh[k * JFE + c];
        #pragma unroll
        for (int k = 0; k < HME; ++k) s += agg[k] * Wh[(DD + k) * JFE + c];
        ho[c] = s;
    }
    float hid[2 * LFE];
    #pragma unroll
    for (int c = 0; c < 2 * LFE; ++c) {
        float s = db1[c];
        #pragma unroll
        for (int k = 0; k < JFE; ++k) s += ho[k] * dW1[k * (2 * LFE) + c];
        hid[c] = silu_f(s);
    }

    if (lane == 0) {
        #pragma unroll
        for (int o = 0; o < LFE; ++o) {
            float s = db2[o];
            #pragma unroll
            for (int c = 0; c < 2 * LFE; ++c) s += hid[c] * dW2[c * LFE + o];
            out[i * 19 + o] = msk ? s : 0.0f;
        }
        out[i * 19 + 16] = msk ? tx : 0.0f;
        out[i * 19 + 17] = msk ? ty : 0.0f;
        out[i * 19 + 18] = msk ? tz : 0.0f;
    }
}

extern "C" void kernel_launch(void* const* d_in, const int* in_sizes, int n_in,
                              void* d_out, int out_size, void* d_ws, size_t ws_size,
                              hipStream_t stream) {
    const float* xl   = (const float*)d_in[0];
    const float* xp   = (const float*)d_in[1];
    const float* posl = (const float*)d_in[2];
    const float* posp = (const float*)d_in[3];
    const float* t    = (const float*)d_in[4];
    const int*   bl   = (const int*)d_in[5];
    const int*   bp   = (const int*)d_in[6];
    const int*   lm   = (const int*)d_in[7];
    const float* aW1  = (const float*)d_in[8];
    const float* ab1  = (const float*)d_in[9];
    const float* aW2  = (const float*)d_in[10];
    const float* ab2  = (const float*)d_in[11];
    const float* fW1  = (const float*)d_in[12];
    const float* fb1  = (const float*)d_in[13];
    const float* fW2  = (const float*)d_in[14];
    const float* fb2  = (const float*)d_in[15];
    const float* rW1  = (const float*)d_in[16];
    const float* rb1  = (const float*)d_in[17];
    const float* rW2  = (const float*)d_in[18];
    const float* rb2  = (const float*)d_in[19];
    const float* dW1  = (const float*)d_in[20];
    const float* db1  = (const float*)d_in[21];
    const float* dW2  = (const float*)d_in[22];
    const float* db2  = (const float*)d_in[23];
    const float* We   = (const float*)d_in[24];
    const float* be   = (const float*)d_in[25];
    const float* Wx   = (const float*)d_in[26];
    const float* bx   = (const float*)d_in[27];
    const float* Wh   = (const float*)d_in[28];
    const float* bh   = (const float*)d_in[29];

    float* ws  = (float*)d_ws;
    float* out = (float*)d_out;

    hipLaunchKernelGGL(encode_kernel, dim3((NTOT + 255) / 256), dim3(256), 0, stream,
                       xl, xp, posl, posp, t, bl, bp, lm,
                       aW1, ab1, aW2, ab2, fW1, fb1, fW2, fb2,
                       rW1, rb1, rW2, rb2, We, be, ws);

    hipLaunchKernelGGL(pair_decode_kernel, dim3(NLIG / 4), dim3(256), 0, stream,
                       We, Wx, bx, lm, Wh, bh, dW1, db1, dW2, db2, ws, out);
}

// Round 3
// 152.378 us; speedup vs baseline: 1.2556x; 1.2556x over previous
//
#include <hip/hip_runtime.h>
#include <math.h>

#define NLIG 512
#define NPROT 2048
#define NTOT 2560
#define LFE 16
#define PFE 21
#define JFE 16
#define HME 16
#define DD 17   // JF+1

// ws layout in floats
#define B_OFF   0          // NTOT*16 = 40960
#define PB_OFF  40960      // NTOT*4  = 10240 (float4: x,y,z,batch-as-int)
#define A_OFF   51200      // NLIG*16 = 8192  (a_i + be)
#define H_OFF   59392      // NLIG*17 = 8704
// total 68096 floats = 272,384 bytes of ws

__device__ __forceinline__ float silu_f(float x) {
    return x / (1.0f + __expf(-x));
}

__global__ __launch_bounds__(256) void encode_kernel(
    const float* __restrict__ xl, const float* __restrict__ xp,
    const float* __restrict__ posl, const float* __restrict__ posp,
    const float* __restrict__ t,
    const int* __restrict__ bl, const int* __restrict__ bp,
    const int* __restrict__ lmask,
    const float* __restrict__ aW1, const float* __restrict__ ab1,
    const float* __restrict__ aW2, const float* __restrict__ ab2,
    const float* __restrict__ fW1, const float* __restrict__ fb1,
    const float* __restrict__ fW2, const float* __restrict__ fb2,
    const float* __restrict__ rW1, const float* __restrict__ rb1,
    const float* __restrict__ rW2, const float* __restrict__ rb2,
    const float* __restrict__ We, const float* __restrict__ be,
    float* __restrict__ ws)
{
    int i = blockIdx.x * 256 + threadIdx.x;
    if (i >= NTOT) return;

    float h[DD];
    if (i < NLIG) {
        float x[LFE];
        #pragma unroll
        for (int k = 0; k < LFE; ++k) x[k] = xl[i * LFE + k];
        bool am = (lmask[i] != 0);
        const float* W1 = am ? aW1 : fW1;
        const float* b1 = am ? ab1 : fb1;
        const float* W2 = am ? aW2 : fW2;
        const float* b2 = am ? ab2 : fb2;
        float hid[2 * LFE];
        #pragma unroll
        for (int c = 0; c < 2 * LFE; ++c) {
            float s = b1[c];
            #pragma unroll
            for (int k = 0; k < LFE; ++k) s += x[k] * W1[k * (2 * LFE) + c];
            hid[c] = silu_f(s);
        }
        #pragma unroll
        for (int o = 0; o < JFE; ++o) {
            float s = b2[o];
            #pragma unroll
            for (int c = 0; c < 2 * LFE; ++c) s += hid[c] * W2[c * JFE + o];
            h[o] = s;
        }
    } else {
        int ip = i - NLIG;
        float x[PFE];
        #pragma unroll
        for (int k = 0; k < PFE; ++k) x[k] = xp[ip * PFE + k];
        float hid[2 * PFE];
        #pragma unroll
        for (int c = 0; c < 2 * PFE; ++c) {
            float s = rb1[c];
            #pragma unroll
            for (int k = 0; k < PFE; ++k) s += x[k] * rW1[k * (2 * PFE) + c];
            hid[c] = silu_f(s);
        }
        #pragma unroll
        for (int o = 0; o < JFE; ++o) {
            float s = rb2[o];
            #pragma unroll
            for (int c = 0; c < 2 * PFE; ++c) s += hid[c] * rW2[c * JFE + o];
            h[o] = s;
        }
    }
    h[DD - 1] = t[0];

    // b_j = h . We[D:2D]  (all nodes)
    #pragma unroll
    for (int m = 0; m < HME; ++m) {
        float s = 0.0f;
        #pragma unroll
        for (int k = 0; k < DD; ++k) s += h[k] * We[(DD + k) * HME + m];
        ws[B_OFF + i * HME + m] = s;
    }

    // packed pos + batch
    float px, py, pz;
    if (i < NLIG) { px = posl[i*3]; py = posl[i*3+1]; pz = posl[i*3+2]; }
    else { int ip = i - NLIG; px = posp[ip*3]; py = posp[ip*3+1]; pz = posp[ip*3+2]; }
    ((float4*)(ws + PB_OFF))[i] = make_float4(px, py, pz, 0.0f);

    if (i < NLIG) {
        // a_i = h . We[:D] + be   (ligand rows are the only i we need)
        #pragma unroll
        for (int m = 0; m < HME; ++m) {
            float s = be[m];
            #pragma unroll
            for (int k = 0; k < DD; ++k) s += h[k] * We[k * HME + m];
            ws[A_OFF + i * HME + m] = s;
        }
        #pragma unroll
        for (int k = 0; k < DD; ++k) ws[H_OFF + i * DD + k] = h[k];
    }
}

// ONE BLOCK (256 threads) per ligand node i. 512 blocks -> 2048 waves, ~8 waves/CU.
// Same-batch j-domain for batch b = [64b,64b+64) ligand  U  [512+256b,+256) protein
// = 320 j's -> each thread evaluates at most 2 pairs. Block-reduce 19 values,
// then decode is parallelized across the block (3 tiny LDS-staged layers).
__global__ __launch_bounds__(256) void pair_decode_kernel(
    const float* __restrict__ We, const float* __restrict__ Wx,
    const float* __restrict__ bx,
    const int* __restrict__ lmask,
    const float* __restrict__ Wh, const float* __restrict__ bh,
    const float* __restrict__ dW1, const float* __restrict__ db1,
    const float* __restrict__ dW2, const float* __restrict__ db2,
    float* __restrict__ ws, float* __restrict__ out)
{
    __shared__ float red[4][20];    // per-wave partials: agg[16], tx, ty, tz
    __shared__ float hl[33];        // h_full(17) ++ agg_total(16)
    __shared__ float tr3[3];
    __shared__ float ho_s[16];
    __shared__ float hid_s[32];

    const int i = blockIdx.x;
    const int tid = threadIdx.x;
    const int lane = tid & 63;
    const int w = tid >> 6;
    const int b = i >> 6;

    const float* Bv = ws + B_OFF;
    const float4* PB = (const float4*)(ws + PB_OFF);
    const float4 pi = PB[i];                 // uniform

    // uniform coefficients (scalarized by compiler)
    float Ai[HME], w2[HME], wx[HME];
    #pragma unroll
    for (int m = 0; m < HME; ++m) {
        Ai[m] = ws[A_OFF + i * HME + m];
        w2[m] = We[2 * DD * HME + m];
        wx[m] = Wx[m];
    }
    const float bxv = bx[0];

    float agg[HME];
    #pragma unroll
    for (int m = 0; m < HME; ++m) agg[m] = 0.0f;
    float tx = 0.0f, ty = 0.0f, tz = 0.0f;

    // pair slots: idx in [0,320); idx<64 -> ligand b*64+idx, else protein 512+b*256+(idx-64)
    #pragma unroll
    for (int s = 0; s < 2; ++s) {
        int idx = tid + s * 256;
        if (idx < 320) {
            int j = (idx < 64) ? (b * 64 + idx) : (NLIG + b * 256 + (idx - 64));
            float4 pj = PB[j];
            float dx = pi.x - pj.x, dy = pi.y - pj.y, dz = pi.z - pj.z;
            float d2 = dx * dx + dy * dy + dz * dz;
            if (d2 < 25.0f) {
                const float4* bj4 = (const float4*)(Bv + j * HME);
                float bj[HME];
                *(float4*)(bj + 0)  = bj4[0];
                *(float4*)(bj + 4)  = bj4[1];
                *(float4*)(bj + 8)  = bj4[2];
                *(float4*)(bj + 12) = bj4[3];
                float e = bxv;
                #pragma unroll
                for (int m = 0; m < HME; ++m) {
                    float pre = Ai[m] + bj[m] + d2 * w2[m];
                    float sv = silu_f(pre);
                    agg[m] += sv;
                    e += sv * wx[m];
                }
                tx += dx * e; ty += dy * e; tz += dz * e;
            }
        }
    }

    // wave butterfly (all lanes get wave-sum)
    #pragma unroll
    for (int off = 1; off <= 32; off <<= 1) {
        #pragma unroll
        for (int m = 0; m < HME; ++m) agg[m] += __shfl_xor(agg[m], off, 64);
        tx += __shfl_xor(tx, off, 64);
        ty += __shfl_xor(ty, off, 64);
        tz += __shfl_xor(tz, off, 64);
    }
    if (lane == 0) {
        #pragma unroll
        for (int m = 0; m < HME; ++m) red[w][m] = agg[m];
        red[w][16] = tx; red[w][17] = ty; red[w][18] = tz;
    }
    __syncthreads();

    // assemble hl = [h_full(17) | agg_total(16)], tr3 = trans
    if (tid < 17) {
        hl[tid] = ws[H_OFF + i * DD + tid];
    } else if (tid < 33) {
        int m = tid - 17;
        hl[tid] = red[0][m] + red[1][m] + red[2][m] + red[3][m];
    } else if (tid < 36) {
        int m = tid - 17;   // 16..18
        tr3[tid - 33] = red[0][m] + red[1][m] + red[2][m] + red[3][m];
    }
    __syncthreads();

    // decode, parallel across block
    if (tid < 16) {
        float s = bh[tid];
        for (int k = 0; k < 33; ++k) s += hl[k] * Wh[k * JFE + tid];
        ho_s[tid] = s;
    }
    __syncthreads();
    if (tid < 32) {
        float s = db1[tid];
        for (int k = 0; k < 16; ++k) s += ho_s[k] * dW1[k * (2 * LFE) + tid];
        hid_s[tid] = silu_f(s);
    }
    __syncthreads();
    if (tid < 19) {
        bool msk = (lmask[i] != 0);
        float v;
        if (tid < 16) {
            float s = db2[tid];
            for (int c = 0; c < 32; ++c) s += hid_s[c] * dW2[c * LFE + tid];
            v = s;
        } else {
            v = tr3[tid - 16];
        }
        out[i * 19 + tid] = msk ? v : 0.0f;
    }
}

extern "C" void kernel_launch(void* const* d_in, const int* in_sizes, int n_in,
                              void* d_out, int out_size, void* d_ws, size_t ws_size,
                              hipStream_t stream) {
    const float* xl   = (const float*)d_in[0];
    const float* xp   = (const float*)d_in[1];
    const float* posl = (const float*)d_in[2];
    const float* posp = (const float*)d_in[3];
    const float* t    = (const float*)d_in[4];
    const int*   bl   = (const int*)d_in[5];
    const int*   bp   = (const int*)d_in[6];
    const int*   lm   = (const int*)d_in[7];
    const float* aW1  = (const float*)d_in[8];
    const float* ab1  = (const float*)d_in[9];
    const float* aW2  = (const float*)d_in[10];
    const float* ab2  = (const float*)d_in[11];
    const float* fW1  = (const float*)d_in[12];
    const float* fb1  = (const float*)d_in[13];
    const float* fW2  = (const float*)d_in[14];
    const float* fb2  = (const float*)d_in[15];
    const float* rW1  = (const float*)d_in[16];
    const float* rb1  = (const float*)d_in[17];
    const float* rW2  = (const float*)d_in[18];
    const float* rb2  = (const float*)d_in[19];
    const float* dW1  = (const float*)d_in[20];
    const float* db1  = (const float*)d_in[21];
    const float* dW2  = (const float*)d_in[22];
    const float* db2  = (const float*)d_in[23];
    const float* We   = (const float*)d_in[24];
    const float* be   = (const float*)d_in[25];
    const float* Wx   = (const float*)d_in[26];
    const float* bx   = (const float*)d_in[27];
    const float* Wh   = (const float*)d_in[28];
    const float* bh   = (const float*)d_in[29];

    float* ws  = (float*)d_ws;
    float* out = (float*)d_out;

    hipLaunchKernelGGL(encode_kernel, dim3((NTOT + 255) / 256), dim3(256), 0, stream,
                       xl, xp, posl, posp, t, bl, bp, lm,
                       aW1, ab1, aW2, ab2, fW1, fb1, fW2, fb2,
                       rW1, rb1, rW2, rb2, We, be, ws);

    hipLaunchKernelGGL(pair_decode_kernel, dim3(NLIG), dim3(256), 0, stream,
                       We, Wx, bx, lm, Wh, bh, dW1, db1, dW2, db2, ws, out);
}

// Round 5
// 120.945 us; speedup vs baseline: 1.5819x; 1.2599x over previous
//
#include <hip/hip_runtime.h>
#include <math.h>

#define NLIG 512
#define NPROT 2048
#define NTOT 2560
#define LFE 16
#define PFE 21
#define JFE 16
#define HME 16
#define DD 17   // JF+1

// ws layout in floats
#define B_OFF   0          // NTOT*16 = 40960
#define PB_OFF  40960      // NTOT*4  = 10240 (float4: x,y,z,0)
#define A_OFF   51200      // NLIG*16 = 8192  (a_i + be)
#define H_OFF   59392      // NLIG*17 = 8704
// total 68096 floats = 272,384 bytes of ws

__device__ __forceinline__ float silu_f(float x) {
    return x / (1.0f + __expf(-x));
}

// Wave-per-node, channel-parallel encode. 2560 waves = 640 blocks x 256 thr.
// CRITICAL: every __shfl here executes with ALL 64 lanes active (ds_bpermute
// returns zero when the SOURCE lane is exec-masked off). Lane-guards are
// applied only at the final stores; compute uses clamped duplicate channels.
__global__ __launch_bounds__(256) void encode_kernel(
    const float* __restrict__ xl, const float* __restrict__ xp,
    const float* __restrict__ posl, const float* __restrict__ posp,
    const float* __restrict__ t,
    const int* __restrict__ lmask,
    const float* __restrict__ aW1, const float* __restrict__ ab1,
    const float* __restrict__ aW2, const float* __restrict__ ab2,
    const float* __restrict__ fW1, const float* __restrict__ fb1,
    const float* __restrict__ fW2, const float* __restrict__ fb2,
    const float* __restrict__ rW1, const float* __restrict__ rb1,
    const float* __restrict__ rW2, const float* __restrict__ rb2,
    const float* __restrict__ We, const float* __restrict__ be,
    float* __restrict__ ws)
{
    const int n    = (blockIdx.x * 256 + threadIdx.x) >> 6;   // node, wave-uniform
    const int lane = threadIdx.x & 63;
    if (n >= NTOT) return;

    const float tv = t[0];
    const int m16 = lane & 15;   // duplicated 16-wide channel
    float hval;                  // lanes 0..15 hold h[0..15] (dups elsewhere)

    if (n < NLIG) {
        // ---- ligand: 16 -> 32 -> 16, mask-selected weights (wave-uniform) ----
        const bool am = (lmask[n] != 0);
        const float* W1 = am ? aW1 : fW1;
        const float* B1 = am ? ab1 : fb1;
        const float* W2 = am ? aW2 : fW2;
        const float* B2 = am ? ab2 : fb2;

        float x = (lane < LFE) ? xl[n * LFE + lane] : 0.0f;

        const int c1 = lane & 31;           // lanes 32..63 duplicate channels 0..31
        float s1 = B1[c1];
        #pragma unroll
        for (int k = 0; k < LFE; ++k)
            s1 += __shfl(x, k, 64) * W1[k * (2 * LFE) + c1];
        float hid = silu_f(s1);             // real on lanes 0..31

        float s2 = B2[m16];
        #pragma unroll
        for (int c = 0; c < 2 * LFE; ++c)
            s2 += __shfl(hid, c, 64) * W2[c * JFE + m16];   // sources 0..31: all active
        hval = s2;
    } else {
        // ---- protein: 21 -> 42 -> 16 ----
        const int ip = n - NLIG;
        float x = (lane < PFE) ? xp[ip * PFE + lane] : 0.0f;

        const int c1 = (lane < 2 * PFE) ? lane : (2 * PFE - 1);  // clamp, stays in range
        float s1 = rb1[c1];
        #pragma unroll
        for (int k = 0; k < PFE; ++k)
            s1 += __shfl(x, k, 64) * rW1[k * (2 * PFE) + c1];
        float hid = silu_f(s1);             // real on lanes 0..41

        float s2 = rb2[m16];
        #pragma unroll
        for (int c = 0; c < 2 * PFE; ++c)
            s2 += __shfl(hid, c, 64) * rW2[c * JFE + m16];  // sources 0..41: all active
        hval = s2;
    }

    // ---- b_j = h . We[D:2D]  (all 64 lanes run the shfl loop) ----
    float sb = tv * We[(DD + 16) * HME + m16];
    #pragma unroll
    for (int k = 0; k < JFE; ++k)
        sb += __shfl(hval, k, 64) * We[(DD + k) * HME + m16];
    if (lane < HME)
        ws[B_OFF + n * HME + lane] = sb;

    // packed pos (x,y,z,0)
    if (lane == 0) {
        const float* p = (n < NLIG) ? (posl + n * 3) : (posp + (n - NLIG) * 3);
        ((float4*)(ws + PB_OFF))[n] = make_float4(p[0], p[1], p[2], 0.0f);
    }

    if (n < NLIG) {
        // a_i = h . We[:D] + be  (full-exec shfl loop, guarded store)
        float sa = be[m16] + tv * We[16 * HME + m16];
        #pragma unroll
        for (int k = 0; k < JFE; ++k)
            sa += __shfl(hval, k, 64) * We[k * HME + m16];
        if (lane < HME)
            ws[A_OFF + n * HME + lane] = sa;
        // store h_full(17); hval read lane-locally (no shfl)
        if (lane < DD)
            ws[H_OFF + n * DD + lane] = (lane < JFE) ? hval : tv;
    }
}

// ONE BLOCK (256 threads) per ligand node i. 512 blocks -> 2048 waves.
// Same-batch j-domain for batch b = [64b,64b+64) ligand U [512+256b,+256) protein
// = 320 j's -> each thread evaluates at most 2 pairs. Block-reduce 19 values,
// then decode parallelized across the block (3 tiny LDS-staged layers).
__global__ __launch_bounds__(256) void pair_decode_kernel(
    const float* __restrict__ We, const float* __restrict__ Wx,
    const float* __restrict__ bx,
    const int* __restrict__ lmask,
    const float* __restrict__ Wh, const float* __restrict__ bh,
    const float* __restrict__ dW1, const float* __restrict__ db1,
    const float* __restrict__ dW2, const float* __restrict__ db2,
    float* __restrict__ ws, float* __restrict__ out)
{
    __shared__ float red[4][20];    // per-wave partials: agg[16], tx, ty, tz
    __shared__ float hl[33];        // h_full(17) ++ agg_total(16)
    __shared__ float tr3[3];
    __shared__ float ho_s[16];
    __shared__ float hid_s[32];

    const int i = blockIdx.x;
    const int tid = threadIdx.x;
    const int lane = tid & 63;
    const int w = tid >> 6;
    const int b = i >> 6;

    const float* Bv = ws + B_OFF;
    const float4* PB = (const float4*)(ws + PB_OFF);
    const float4 pi = PB[i];                 // uniform

    float Ai[HME], w2[HME], wx[HME];
    #pragma unroll
    for (int m = 0; m < HME; ++m) {
        Ai[m] = ws[A_OFF + i * HME + m];
        w2[m] = We[2 * DD * HME + m];
        wx[m] = Wx[m];
    }
    const float bxv = bx[0];

    float agg[HME];
    #pragma unroll
    for (int m = 0; m < HME; ++m) agg[m] = 0.0f;
    float tx = 0.0f, ty = 0.0f, tz = 0.0f;

    #pragma unroll
    for (int s = 0; s < 2; ++s) {
        int idx = tid + s * 256;
        if (idx < 320) {
            int j = (idx < 64) ? (b * 64 + idx) : (NLIG + b * 256 + (idx - 64));
            float4 pj = PB[j];
            float dx = pi.x - pj.x, dy = pi.y - pj.y, dz = pi.z - pj.z;
            float d2 = dx * dx + dy * dy + dz * dz;
            if (d2 < 25.0f) {
                const float4* bj4 = (const float4*)(Bv + j * HME);
                float bj[HME];
                *(float4*)(bj + 0)  = bj4[0];
                *(float4*)(bj + 4)  = bj4[1];
                *(float4*)(bj + 8)  = bj4[2];
                *(float4*)(bj + 12) = bj4[3];
                float e = bxv;
                #pragma unroll
                for (int m = 0; m < HME; ++m) {
                    float pre = Ai[m] + bj[m] + d2 * w2[m];
                    float sv = silu_f(pre);
                    agg[m] += sv;
                    e += sv * wx[m];
                }
                tx += dx * e; ty += dy * e; tz += dz * e;
            }
        }
    }

    // full-exec butterfly reduce (all 64 lanes active)
    #pragma unroll
    for (int off = 1; off <= 32; off <<= 1) {
        #pragma unroll
        for (int m = 0; m < HME; ++m) agg[m] += __shfl_xor(agg[m], off, 64);
        tx += __shfl_xor(tx, off, 64);
        ty += __shfl_xor(ty, off, 64);
        tz += __shfl_xor(tz, off, 64);
    }
    if (lane == 0) {
        #pragma unroll
        for (int m = 0; m < HME; ++m) red[w][m] = agg[m];
        red[w][16] = tx; red[w][17] = ty; red[w][18] = tz;
    }
    __syncthreads();

    if (tid < 17) {
        hl[tid] = ws[H_OFF + i * DD + tid];
    } else if (tid < 33) {
        int m = tid - 17;
        hl[tid] = red[0][m] + red[1][m] + red[2][m] + red[3][m];
    } else if (tid < 36) {
        int m = tid - 17;   // 16..18
        tr3[tid - 33] = red[0][m] + red[1][m] + red[2][m] + red[3][m];
    }
    __syncthreads();

    if (tid < 16) {
        float s = bh[tid];
        for (int k = 0; k < 33; ++k) s += hl[k] * Wh[k * JFE + tid];
        ho_s[tid] = s;
    }
    __syncthreads();
    if (tid < 32) {
        float s = db1[tid];
        for (int k = 0; k < 16; ++k) s += ho_s[k] * dW1[k * (2 * LFE) + tid];
        hid_s[tid] = silu_f(s);
    }
    __syncthreads();
    if (tid < 19) {
        bool msk = (lmask[i] != 0);
        float v;
        if (tid < 16) {
            float s = db2[tid];
            for (int c = 0; c < 32; ++c) s += hid_s[c] * dW2[c * LFE + tid];
            v = s;
        } else {
            v = tr3[tid - 16];
        }
        out[i * 19 + tid] = msk ? v : 0.0f;
    }
}

extern "C" void kernel_launch(void* const* d_in, const int* in_sizes, int n_in,
                              void* d_out, int out_size, void* d_ws, size_t ws_size,
                              hipStream_t stream) {
    const float* xl   = (const float*)d_in[0];
    const float* xp   = (const float*)d_in[1];
    const float* posl = (const float*)d_in[2];
    const float* posp = (const float*)d_in[3];
    const float* t    = (const float*)d_in[4];
    const int*   lm   = (const int*)d_in[7];
    const float* aW1  = (const float*)d_in[8];
    const float* ab1  = (const float*)d_in[9];
    const float* aW2  = (const float*)d_in[10];
    const float* ab2  = (const float*)d_in[11];
    const float* fW1  = (const float*)d_in[12];
    const float* fb1  = (const float*)d_in[13];
    const float* fW2  = (const float*)d_in[14];
    const float* fb2  = (const float*)d_in[15];
    const float* rW1  = (const float*)d_in[16];
    const float* rb1  = (const float*)d_in[17];
    const float* rW2  = (const float*)d_in[18];
    const float* rb2  = (const float*)d_in[19];
    const float* dW1  = (const float*)d_in[20];
    const float* db1  = (const float*)d_in[21];
    const float* dW2  = (const float*)d_in[22];
    const float* db2  = (const float*)d_in[23];
    const float* We   = (const float*)d_in[24];
    const float* be   = (const float*)d_in[25];
    const float* Wx   = (const float*)d_in[26];
    const float* bx   = (const float*)d_in[27];
    const float* Wh   = (const float*)d_in[28];
    const float* bh   = (const float*)d_in[29];

    float* ws  = (float*)d_ws;
    float* out = (float*)d_out;

    hipLaunchKernelGGL(encode_kernel, dim3(NTOT * 64 / 256), dim3(256), 0, stream,
                       xl, xp, posl, posp, t, lm,
                       aW1, ab1, aW2, ab2, fW1, fb1, fW2, fb2,
                       rW1, rb1, rW2, rb2, We, be, ws);

    hipLaunchKernelGGL(pair_decode_kernel, dim3(NLIG), dim3(256), 0, stream,
                       We, Wx, bx, lm, Wh, bh, dW1, db1, dW2, db2, ws, out);
}